// Round 1
// baseline (944.351 us; speedup 1.0000x reference)
//
#include <hip/hip_runtime.h>

// ---------------------------------------------------------------------------
// ConvBERT layer forward, bf16 compute / fp32 accumulate.
// B=8 S=1024 H=1536 NH=8 HD=96 AH=768 K=7 IM=3072
// Round 8: gemm256 — 256x256 tile, BK=64, 8 waves, 128KB LDS double-buffer,
//          4-phase K-loop with counted vmcnt(4) (T3+T4), XOR bank swizzle
//          via pre-swizzled global_load_lds source (T2), setprio around the
//          MFMA clusters (T5), bijective XCD tile swizzle (T1).
//          Old 128x128 gemm_tile kept only for the tiny ck GEMM (N=56).
// ---------------------------------------------------------------------------

typedef __bf16 bf16_t;
typedef short s16x8 __attribute__((ext_vector_type(8)));   // 8 bf16 in 4 VGPRs
typedef float f32x4 __attribute__((ext_vector_type(4)));

#define BB  8
#define SS  1024
#define HH  1536
#define NHH 8
#define HDD 96
#define AHH 768
#define IMM 3072

__device__ __forceinline__ float rd_adapt(const void* p, long long i, int isbf) {
    return isbf ? (float)((const bf16_t*)p)[i] : ((const float*)p)[i];
}

// tanh-form GELU: max |diff| vs exact erf-GELU ~3e-3, far under bf16 budget
__device__ __forceinline__ float gelu_f(float v) {
    float u = v * (0.7978845608f + 0.0356774081f * v * v);
    float e = __expf(2.0f * u);
    float t = 1.0f - 2.0f / (e + 1.0f);
    return 0.5f * v * (1.0f + t);
}

// async global->LDS, 16B per lane; lds base must be wave-uniform
__device__ __forceinline__ void gl2lds16(const bf16_t* g, bf16_t* l) {
    __builtin_amdgcn_global_load_lds(
        (__attribute__((address_space(1))) const void*)g,
        (__attribute__((address_space(3))) void*)l, 16, 0, 0);
}

#define FENCE() asm volatile("" ::: "memory")
#define BARRIER() do { FENCE(); __builtin_amdgcn_s_barrier(); FENCE(); } while (0)

// ---------------------------------------------------------------------------
// dtype probe: bf16 vs fp32 inputs. flag=1 -> bf16.
// ---------------------------------------------------------------------------
__global__ __launch_bounds__(256)
void detect_kernel(const void* __restrict__ embed, int* __restrict__ flag)
{
    __shared__ int cnt[256];
    int t = threadIdx.x;
    float x = (float)((const bf16_t*)embed)[t];
    float a = fabsf(x);
    cnt[t] = (a > 1e-3f && a < 50.0f) ? 1 : 0;
    __syncthreads();
    for (int o = 128; o > 0; o >>= 1) { if (t < o) cnt[t] += cnt[t + o]; __syncthreads(); }
    if (t == 0) *flag = (cnt[0] >= 205) ? 1 : 0;
}

__global__ __launch_bounds__(256)
void convert_embed(const void* __restrict__ in, bf16_t* __restrict__ out,
                   const int* __restrict__ flagp)
{
    int isbf = *flagp;
    long long i0 = ((long long)blockIdx.x * 256 + threadIdx.x) * 8;
    if (isbf) {
        *(s16x8*)(out + i0) = *(const s16x8*)((const bf16_t*)in + i0);
    } else {
        const float* f = (const float*)in;
        #pragma unroll
        for (int j = 0; j < 8; j++) out[i0 + j] = (bf16_t)f[i0 + j];
    }
}

// concat bq|bk|bv|bco -> cbias[3072] bf16
__global__ __launch_bounds__(256)
void concat_bias(const void* __restrict__ b0, const void* __restrict__ b1,
                 const void* __restrict__ b2, const void* __restrict__ b3,
                 bf16_t* __restrict__ out, const int* __restrict__ flagp)
{
    int isbf = *flagp;
    int t = blockIdx.x * 256 + threadIdx.x;   // < 3072
    int sel = t / 768, off = t - sel * 768;
    const void* src = (sel == 0) ? b0 : (sel == 1) ? b1 : (sel == 2) ? b2 : b3;
    out[t] = (bf16_t)rd_adapt(src, off, isbf);
}

// ---------------------------------------------------------------------------
// gemm256: 256x256 tile, BK=64, 512 threads = 8 waves (2M x 4N), each wave
// owns a 128x64 output sub-tile (8x4 frags of 16x16, K-sub 2 per K-tile).
//
// LDS (128 KiB, all linear row-major [256][64] bf16, row stride 128B):
//   A buf0 @ 0       A buf1 @ 32768
//   B buf0 @ 65536   B buf1 @ 98304
// Swizzle (T2): LDS[off] holds logical element off ^ ((row&7)<<4). The
// global_load_lds dest stays linear; the SOURCE column is pre-swizzled and
// the ds_read address applies the same XOR (involution, rule #21).
//
// Stage schedule (derived from read-consumption; raw s_barrier per phase,
// vmcnt never drained below 4 in the loop):
//   tile t ph1: read A-half0 frags + B own lower frags; stage A-half1(t+1)
//   tile t ph2: read B own upper frags;                  stage B-half1(t+1)
//   tile t ph3: read A-half1 frags;                      stage B-half0(t+2)
//   tile t ph4: (regs resident);                         stage A-half0(t+2)
//               s_waitcnt vmcnt(4)  -> all of tile t+1 landed
// Same-buffer stages (ph3/ph4) only touch regions whose last ds_read
// completed a full barrier earlier. Requires M%256==0, N%256==0, Kd%64==0.
// ---------------------------------------------------------------------------
__global__ __launch_bounds__(512, 2)
void gemm256(const bf16_t* __restrict__ A, const bf16_t* __restrict__ Bt,
             bf16_t* __restrict__ C, const void* __restrict__ bias,
             const bf16_t* __restrict__ emul, int lde, const int* __restrict__ flagp,
             int M, int N, int Kd, int lda, int ldb, int ldc, int act, int tilesN)
{
    __shared__ bf16_t Sm[65536];   // 128 KiB
    char* smb = (char*)Sm;
    int isbf = flagp ? *flagp : 1;

    // bijective XCD remap (m204) of the linear tile id; n fastest inside
    int nwg = gridDim.x;
    int orig = blockIdx.x;
    int q = nwg >> 3, r = nwg & 7;
    int xcd = orig & 7, lid = orig >> 3;
    int wg = (xcd < r ? xcd * (q + 1) : r * (q + 1) + (xcd - r) * q) + lid;
    int row0 = (wg / tilesN) * 256;
    int col0 = (wg % tilesN) * 256;

    int tid = threadIdx.x;
    int wave = tid >> 6, lane = tid & 63;
    int wm = wave >> 2, wn = wave & 3;
    int lm = lane & 15, kq = lane >> 4;

    // ---- staging geometry: wave w loads chunks {2w,2w+1} of each 16KB half
    int srow = lane >> 3;                       // 0..7 row within 1KB chunk
    int scol = 8 * ((lane & 7) ^ srow);         // pre-swizzled source col (bf16)

    auto stageA2 = [&](int kt, int h, int bufo) {
        #pragma unroll
        for (int l = 0; l < 2; l++) {
            int rloc = h * 128 + (2 * wave + l) * 8 + srow;
            gl2lds16(A + (long long)(row0 + rloc) * lda + kt * 64 + scol,
                     (bf16_t*)(smb + bufo * 32768 + h * 16384 + (2 * wave + l) * 1024));
        }
    };
    auto stageB2 = [&](int kt, int h, int bufo) {
        #pragma unroll
        for (int l = 0; l < 2; l++) {
            int rloc = h * 128 + (2 * wave + l) * 8 + srow;
            gl2lds16(Bt + (long long)(col0 + rloc) * ldb + kt * 64 + scol,
                     (bf16_t*)(smb + 65536 + bufo * 32768 + h * 16384 + (2 * wave + l) * 1024));
        }
    };

    // ---- fragment-read address constants (swizzled) ----
    int xo = (lm & 7) << 4;
    int cofs[2];                                // byte col offset for ksub 0/1
    cofs[0] = (kq * 16) ^ xo;
    cofs[1] = (64 + kq * 16) ^ xo;
    int aoffs[8];
    #pragma unroll
    for (int ip = 0; ip < 8; ip++) aoffs[ip] = (wm * 128 + ip * 16 + lm) * 128;
    int boffs[4];
    #pragma unroll
    for (int j = 0; j < 4; j++) boffs[j] = 65536 + (wn * 64 + j * 16 + lm) * 128;

    f32x4 acc[8][4] = {};
    s16x8 af[4][2], bf0[2][2], bf1[2][2];

    int KT = Kd >> 6;

    // ---- prologue: tile0 (4 halves) + B0(1), A0(1); then vmcnt(4) ----
    stageA2(0, 0, 0);
    stageB2(0, 0, 0);
    stageA2(0, 1, 0);
    stageB2(0, 1, 0);
    int k1 = min(1, KT - 1);
    stageB2(k1, 0, 1);
    stageA2(k1, 0, 1);
    asm volatile("s_waitcnt vmcnt(4)" ::: "memory");
    BARRIER();

    for (int t = 0; t < KT; t++) {
        int buf = t & 1;
        int bA = buf * 32768;
        int ob = buf ^ 1;
        int tn1 = min(t + 1, KT - 1), tn2 = min(t + 2, KT - 1);

        // ---------------- phase 1: Q(M0,N-low) ----------------
        #pragma unroll
        for (int i = 0; i < 4; i++)
            #pragma unroll
            for (int s = 0; s < 2; s++)
                af[i][s] = *(const s16x8*)(smb + bA + aoffs[i] + cofs[s]);
        #pragma unroll
        for (int j = 0; j < 2; j++)
            #pragma unroll
            for (int s = 0; s < 2; s++)
                bf0[j][s] = *(const s16x8*)(smb + bA + boffs[j] + cofs[s]);
        stageA2(tn1, 1, ob);
        BARRIER();
        asm volatile("s_waitcnt lgkmcnt(0)" ::: "memory");
        __builtin_amdgcn_sched_barrier(0);
        __builtin_amdgcn_s_setprio(1);
        #pragma unroll
        for (int i = 0; i < 4; i++)
            #pragma unroll
            for (int j = 0; j < 2; j++) {
                acc[i][j] = __builtin_amdgcn_mfma_f32_16x16x32_bf16(af[i][0], bf0[j][0], acc[i][j], 0, 0, 0);
                acc[i][j] = __builtin_amdgcn_mfma_f32_16x16x32_bf16(af[i][1], bf0[j][1], acc[i][j], 0, 0, 0);
            }
        __builtin_amdgcn_s_setprio(0);
        BARRIER();

        // ---------------- phase 2: Q(M0,N-high) ----------------
        #pragma unroll
        for (int j = 0; j < 2; j++)
            #pragma unroll
            for (int s = 0; s < 2; s++)
                bf1[j][s] = *(const s16x8*)(smb + bA + boffs[2 + j] + cofs[s]);
        stageB2(tn1, 1, ob);
        BARRIER();
        asm volatile("s_waitcnt lgkmcnt(0)" ::: "memory");
        __builtin_amdgcn_sched_barrier(0);
        __builtin_amdgcn_s_setprio(1);
        #pragma unroll
        for (int i = 0; i < 4; i++)
            #pragma unroll
            for (int j = 0; j < 2; j++) {
                acc[i][2 + j] = __builtin_amdgcn_mfma_f32_16x16x32_bf16(af[i][0], bf1[j][0], acc[i][2 + j], 0, 0, 0);
                acc[i][2 + j] = __builtin_amdgcn_mfma_f32_16x16x32_bf16(af[i][1], bf1[j][1], acc[i][2 + j], 0, 0, 0);
            }
        __builtin_amdgcn_s_setprio(0);
        BARRIER();

        // ---------------- phase 3: Q(M1,N-high) ----------------
        #pragma unroll
        for (int i = 0; i < 4; i++)
            #pragma unroll
            for (int s = 0; s < 2; s++)
                af[i][s] = *(const s16x8*)(smb + bA + aoffs[4 + i] + cofs[s]);
        stageB2(tn2, 0, buf);
        BARRIER();
        asm volatile("s_waitcnt lgkmcnt(0)" ::: "memory");
        __builtin_amdgcn_sched_barrier(0);
        __builtin_amdgcn_s_setprio(1);
        #pragma unroll
        for (int i = 0; i < 4; i++)
            #pragma unroll
            for (int j = 0; j < 2; j++) {
                acc[4 + i][2 + j] = __builtin_amdgcn_mfma_f32_16x16x32_bf16(af[i][0], bf1[j][0], acc[4 + i][2 + j], 0, 0, 0);
                acc[4 + i][2 + j] = __builtin_amdgcn_mfma_f32_16x16x32_bf16(af[i][1], bf1[j][1], acc[4 + i][2 + j], 0, 0, 0);
            }
        __builtin_amdgcn_s_setprio(0);
        BARRIER();

        // ---------------- phase 4: Q(M1,N-low) ----------------
        stageA2(tn2, 0, buf);
        BARRIER();
        __builtin_amdgcn_s_setprio(1);
        #pragma unroll
        for (int i = 0; i < 4; i++)
            #pragma unroll
            for (int j = 0; j < 2; j++) {
                acc[4 + i][j] = __builtin_amdgcn_mfma_f32_16x16x32_bf16(af[i][0], bf0[j][0], acc[4 + i][j], 0, 0, 0);
                acc[4 + i][j] = __builtin_amdgcn_mfma_f32_16x16x32_bf16(af[i][1], bf0[j][1], acc[4 + i][j], 0, 0, 0);
            }
        __builtin_amdgcn_s_setprio(0);
        asm volatile("s_waitcnt vmcnt(4)" ::: "memory");   // tile t+1 fully landed
        BARRIER();
    }

    // ---- epilogue: D row = kq*4 + r, col = lm (m89/m91-verified) ----
    #pragma unroll
    for (int j = 0; j < 4; j++) {
        int gcol = col0 + wn * 64 + j * 16 + lm;
        float bv = bias ? rd_adapt(bias, gcol, isbf) : 0.0f;
        #pragma unroll
        for (int ip = 0; ip < 8; ip++) {
            int grow0 = row0 + wm * 128 + ip * 16 + kq * 4;
            #pragma unroll
            for (int r = 0; r < 4; r++) {
                float v = acc[ip][j][r] + bv;
                if (emul) v *= (float)emul[(long long)(grow0 + r) * lde + gcol];
                if (act) v = gelu_f(v);
                C[(long long)(grow0 + r) * ldc + gcol] = (bf16_t)v;
            }
        }
    }
}

// ---------------------------------------------------------------------------
// Legacy 128x128 GEMM (kept for the tiny ck GEMM, N=56 padded to 128).
// ---------------------------------------------------------------------------
__global__ __launch_bounds__(256)
void gemm_tile(const bf16_t* __restrict__ A, const bf16_t* __restrict__ Bt,
               bf16_t* __restrict__ C, const void* __restrict__ bias, long long biasOff,
               const bf16_t* __restrict__ emul, int lde, const int* __restrict__ flagp,
               int M, int N, int Kd, int lda, int ldb, int ldc,
               float scale, int act, int beta, int nlim)
{
    __shared__ bf16_t Sm[16384];   // As: [2][128][32] at 0; Bs: [2][128][32] at 8192

    int isbf = flagp ? *flagp : 1;
    int tid  = threadIdx.x;
    int wave = tid >> 6, lane = tid & 63;
    int wm = wave >> 1, wn = wave & 1;
    int row0 = blockIdx.x * 128;
    int col0 = blockIdx.y * 128;
    int lm = lane & 15;
    int kq = lane >> 4;

    int sr = tid >> 2;            // 0..63
    int sc = (tid & 3) * 8;       // 0,8,16,24
    const bf16_t* ga0 = A + (long long)(row0 + sr) * lda + sc;
    const bf16_t* ga1 = A + (long long)(row0 + 64 + sr) * lda + sc;
    int br0 = min(col0 + sr, nlim);
    int br1 = min(col0 + 64 + sr, nlim);
    const bf16_t* gb0 = Bt + (long long)br0 * ldb + sc;
    const bf16_t* gb1 = Bt + (long long)br1 * ldb + sc;
    bf16_t* lw = Sm + wave * 512;   // wave-uniform staging base

    f32x4 acc[4][4] = {};

    for (int k0 = 0; k0 < Kd; k0 += 64) {
        #pragma unroll
        for (int h = 0; h < 2; h++) {
            int kh = k0 + h * 32;
            gl2lds16(ga0 + kh, lw + h * 4096);
            gl2lds16(ga1 + kh, lw + h * 4096 + 2048);
            gl2lds16(gb0 + kh, lw + 8192 + h * 4096);
            gl2lds16(gb1 + kh, lw + 8192 + h * 4096 + 2048);
        }
        __syncthreads();

        s16x8 af[2][4], bfr[2][4];
        #pragma unroll
        for (int h = 0; h < 2; h++) {
            #pragma unroll
            for (int i = 0; i < 4; i++)
                af[h][i] = *(const s16x8*)(Sm + h * 4096 + (wm * 64 + i * 16 + lm) * 32 + kq * 8);
            #pragma unroll
            for (int j = 0; j < 4; j++)
                bfr[h][j] = *(const s16x8*)(Sm + 8192 + h * 4096 + (wn * 64 + j * 16 + lm) * 32 + kq * 8);
        }
        #pragma unroll
        for (int i = 0; i < 4; i++)
            #pragma unroll
            for (int j = 0; j < 4; j++) {
                acc[i][j] = __builtin_amdgcn_mfma_f32_16x16x32_bf16(af[0][i], bfr[0][j], acc[i][j], 0, 0, 0);
                acc[i][j] = __builtin_amdgcn_mfma_f32_16x16x32_bf16(af[1][i], bfr[1][j], acc[i][j], 0, 0, 0);
            }
        __syncthreads();
    }

    // epilogue: D row = kq*4 + r, col = lm (m89/m91-verified)
    #pragma unroll
    for (int j = 0; j < 4; j++) {
        int gcol = col0 + wn * 64 + j * 16 + lm;
        if (gcol >= N) continue;
        float bv = bias ? rd_adapt(bias, biasOff + gcol, isbf) : 0.0f;
        #pragma unroll
        for (int i = 0; i < 4; i++) {
            int grow0 = row0 + wm * 64 + i * 16 + kq * 4;
            #pragma unroll
            for (int r = 0; r < 4; r++) {
                float v = acc[i][j][r] * scale + bv;
                long long ci = (long long)(grow0 + r) * ldc + gcol;
                if (beta) v += (float)C[ci];
                if (emul) v *= (float)emul[(long long)(grow0 + r) * lde + gcol];
                if (act) v = gelu_f(v);
                C[ci] = (bf16_t)v;
            }
        }
    }
}

// ---------------------------------------------------------------------------
// Fused flash attention. grid = (64 bh, 8 q-tiles), block = 256.
// bh fastest -> XCD = bh%8 -> all q-tiles of one (b,h) share an XCD's L2.
// ---------------------------------------------------------------------------
__global__ __launch_bounds__(256, 2)
void flash_attn(const bf16_t* __restrict__ qkv, const bf16_t* __restrict__ vT,
                bf16_t* __restrict__ ctxcat)
{
    const float ascale = 0.1020620726159658f;   // 1/sqrt(96)
    __shared__ bf16_t Pl[4 * 32 * 136];         // per-wave P[32][136] (pad 8)

    int bh = blockIdx.x;
    int b = bh >> 3, h = bh & 7;
    const bf16_t* Qp = qkv  + (long long)b * SS * 3072 + h * HDD;
    const bf16_t* Kp = qkv  + (long long)b * SS * 3072 + 768 + h * HDD;
    const bf16_t* Vt = vT   + (long long)b * AHH * SS + (long long)h * HDD * SS;
    bf16_t*       Op = ctxcat + (long long)b * SS * HH + h * HDD;

    int tid = threadIdx.x, wave = tid >> 6, lane = tid & 63;
    int lm = lane & 15, kq = lane >> 4;
    int q0 = blockIdx.y * 128 + wave * 32;
    bf16_t* Pw = Pl + wave * 32 * 136;

    s16x8 aq[2][3];
    #pragma unroll
    for (int i = 0; i < 2; i++)
        #pragma unroll
        for (int kf = 0; kf < 3; kf++)
            aq[i][kf] = *(const s16x8*)(Qp + (long long)(q0 + i * 16 + lm) * 3072 + kf * 32 + kq * 8);

    f32x4 Oacc[2][6] = {};
    float mrow[2][4], lrow[2][4];
    #pragma unroll
    for (int i = 0; i < 2; i++)
        #pragma unroll
        for (int r = 0; r < 4; r++) { mrow[i][r] = -1e30f; lrow[i][r] = 0.0f; }

    for (int kt = 0; kt < 8; kt++) {
        f32x4 S[2][8] = {};
        #pragma unroll
        for (int j = 0; j < 8; j++) {
            s16x8 bk[3];
            #pragma unroll
            for (int kf = 0; kf < 3; kf++)
                bk[kf] = *(const s16x8*)(Kp + (long long)(kt * 128 + j * 16 + lm) * 3072 + kf * 32 + kq * 8);
            #pragma unroll
            for (int i = 0; i < 2; i++)
                #pragma unroll
                for (int kf = 0; kf < 3; kf++)
                    S[i][j] = __builtin_amdgcn_mfma_f32_16x16x32_bf16(aq[i][kf], bk[kf], S[i][j], 0, 0, 0);
        }

        float mnew[2][4];
        #pragma unroll
        for (int i = 0; i < 2; i++) {
            #pragma unroll
            for (int r = 0; r < 4; r++) {
                float mx = -1e30f;
                #pragma unroll
                for (int j = 0; j < 8; j++) mx = fmaxf(mx, S[i][j][r]);
                #pragma unroll
                for (int msk = 1; msk <= 8; msk <<= 1) mx = fmaxf(mx, __shfl_xor(mx, msk));
                mnew[i][r] = fmaxf(mrow[i][r], mx * ascale);
            }
        }
        #pragma unroll
        for (int i = 0; i < 2; i++) {
            #pragma unroll
            for (int r = 0; r < 4; r++) {
                float al = __expf(mrow[i][r] - mnew[i][r]);
                lrow[i][r] *= al;
                #pragma unroll
                for (int n = 0; n < 6; n++) Oacc[i][n][r] *= al;
                mrow[i][r] = mnew[i][r];
            }
        }
        float psum[2][4] = {};
        __syncthreads();
        #pragma unroll
        for (int i = 0; i < 2; i++) {
            #pragma unroll
            for (int j = 0; j < 8; j++) {
                #pragma unroll
                for (int r = 0; r < 4; r++) {
                    float p = __expf(S[i][j][r] * ascale - mnew[i][r]);
                    psum[i][r] += p;
                    Pw[(i * 16 + kq * 4 + r) * 136 + j * 16 + lm] = (bf16_t)p;
                }
            }
        }
        #pragma unroll
        for (int i = 0; i < 2; i++) {
            #pragma unroll
            for (int r = 0; r < 4; r++) {
                float t = psum[i][r];
                #pragma unroll
                for (int msk = 1; msk <= 8; msk <<= 1) t += __shfl_xor(t, msk);
                lrow[i][r] += t;
            }
        }
        __syncthreads();

        s16x8 ap[2][4];
        #pragma unroll
        for (int i = 0; i < 2; i++)
            #pragma unroll
            for (int kf = 0; kf < 4; kf++)
                ap[i][kf] = *(const s16x8*)(Pw + (i * 16 + lm) * 136 + kf * 32 + kq * 8);
        #pragma unroll
        for (int n = 0; n < 6; n++) {
            s16x8 bv[4];
            #pragma unroll
            for (int kf = 0; kf < 4; kf++)
                bv[kf] = *(const s16x8*)(Vt + (long long)(n * 16 + lm) * SS + kt * 128 + kf * 32 + kq * 8);
            #pragma unroll
            for (int i = 0; i < 2; i++)
                #pragma unroll
                for (int kf = 0; kf < 4; kf++)
                    Oacc[i][n] = __builtin_amdgcn_mfma_f32_16x16x32_bf16(ap[i][kf], bv[kf], Oacc[i][n], 0, 0, 0);
        }
    }

    #pragma unroll
    for (int i = 0; i < 2; i++) {
        #pragma unroll
        for (int n = 0; n < 6; n++) {
            #pragma unroll
            for (int r = 0; r < 4; r++) {
                int row = q0 + i * 16 + kq * 4 + r;
                int col = n * 16 + lm;
                Op[(long long)row * HH + col] = (bf16_t)(Oacc[i][n][r] / lrow[i][r]);
            }
        }
    }
}

// ---------------------------------------------------------------------------
// Adaptive tiled transpose with zero-padding beyond C columns.
// ---------------------------------------------------------------------------
__global__ __launch_bounds__(256)
void transpose_pad(const void* __restrict__ in, bf16_t* __restrict__ out,
                   int R, int C, int ldin, long long inOff,
                   long long sInB, long long sOutB, const int* __restrict__ flagp)
{
    __shared__ bf16_t t[32][33];
    int isbf = flagp ? *flagp : 1;
    int z = blockIdx.z;
    long long base = inOff + (long long)z * sInB;
    bf16_t* op = out + (long long)z * sOutB;
    int tx = threadIdx.x & 31, ty = threadIdx.x >> 5;
    int cb = blockIdx.x * 32, rb = blockIdx.y * 32;
    #pragma unroll
    for (int rr = ty; rr < 32; rr += 8) {
        int r = rb + rr, c = cb + tx;
        t[rr][tx] = (c < C) ? (bf16_t)rd_adapt(in, base + (long long)r * ldin + c, isbf)
                            : (bf16_t)0.0f;
    }
    __syncthreads();
    #pragma unroll
    for (int rr = ty; rr < 32; rr += 8) {
        int c = cb + rr;
        op[(long long)c * R + rb + tx] = t[tx][rr];
    }
}

// depthwise conv k=7, 'same' padding along S
__global__ __launch_bounds__(256)
void dconv_kernel(const bf16_t* __restrict__ ebuf, const void* __restrict__ dw,
                  bf16_t* __restrict__ out, const int* __restrict__ flagp)
{
    int isbf = *flagp;
    long long i = (long long)blockIdx.x * 256 + threadIdx.x;   // < B*S*H
    int c = (int)(i % HH);
    long long bs = i / HH;
    int s = (int)(bs % SS);
    float acc = 0.0f;
    #pragma unroll
    for (int k = 0; k < 7; k++) {
        int ss = s + k - 3;
        if (ss >= 0 && ss < SS)
            acc += (float)ebuf[(bs + (k - 3)) * HH + c] * rd_adapt(dw, c * 7 + k, isbf);
    }
    out[i] = (bf16_t)acc;
}

// ck softmax over k=7 per (b,s,h)
__global__ __launch_bounds__(256)
void ck_softmax(const bf16_t* __restrict__ ck, float* __restrict__ ckp)
{
    int i = blockIdx.x * 256 + threadIdx.x;   // < B*S*NH
    if (i >= BB * SS * NHH) return;
    int h = i % NHH;
    long long bs = i / NHH;
    const bf16_t* src = ck + bs * 64 + h * 7;
    float v[7], mx = -1e30f;
    #pragma unroll
    for (int k = 0; k < 7; k++) { v[k] = (float)src[k]; mx = fmaxf(mx, v[k]); }
    float sum = 0.0f;
    #pragma unroll
    for (int k = 0; k < 7; k++) { v[k] = expf(v[k] - mx); sum += v[k]; }
    float inv = 1.0f / sum;
    float* dst = ckp + bs * 56 + h * 7;
    #pragma unroll
    for (int k = 0; k < 7; k++) dst[k] = v[k] * inv;
}

// conv_out -> right half (cols 768..1535) of ctxcat; co has row stride ldco
__global__ __launch_bounds__(256)
void conv_out_kernel(const bf16_t* __restrict__ co, int ldco,
                     const float* __restrict__ ckp, bf16_t* __restrict__ ctxcat)
{
    long long i = (long long)blockIdx.x * 256 + threadIdx.x;   // < B*S*AH
    int hd = (int)(i % AHH);
    long long bs = i / AHH;
    int s = (int)(bs % SS);
    int h = hd / HDD;
    const float* w = ckp + bs * 56 + h * 7;
    float acc = 0.0f;
    #pragma unroll
    for (int k = 0; k < 7; k++) {
        int ss = s + k - 3;
        if (ss >= 0 && ss < SS)
            acc += (float)co[(bs + (k - 3)) * ldco + hd] * w[k];
    }
    ctxcat[bs * HH + AHH + hd] = (bf16_t)acc;
}

// LayerNorm over 1536 of (y + res)
__global__ __launch_bounds__(256)
void ln_kernel(const bf16_t* __restrict__ y, const bf16_t* __restrict__ res,
               const void* __restrict__ g, const void* __restrict__ bta,
               bf16_t* __restrict__ outb, const int* __restrict__ flagp)
{
    int isbf = *flagp;
    long long row = blockIdx.x;
    const bf16_t* yp = y + row * HH;
    const bf16_t* rp = res + row * HH;
    int tid = threadIdx.x;
    float x[6], s = 0.0f, s2 = 0.0f;
    #pragma unroll
    for (int i = 0; i < 6; i++) {
        int c = tid + i * 256;
        float v = (float)yp[c] + (float)rp[c];
        x[i] = v; s += v; s2 += v * v;
    }
    __shared__ float sa[256], sb[256];
    sa[tid] = s; sb[tid] = s2; __syncthreads();
    for (int o = 128; o > 0; o >>= 1) {
        if (tid < o) { sa[tid] += sa[tid + o]; sb[tid] += sb[tid + o]; }
        __syncthreads();
    }
    float mean = sa[0] * (1.0f / HH);
    float var  = sb[0] * (1.0f / HH) - mean * mean;
    float inv  = rsqrtf(var + 1e-12f);
    #pragma unroll
    for (int i = 0; i < 6; i++) {
        int c = tid + i * 256;
        float v = (x[i] - mean) * inv * rd_adapt(g, c, isbf) + rd_adapt(bta, c, isbf);
        outb[row * HH + c] = (bf16_t)v;
    }
}

// two-phase maxpool
__global__ __launch_bounds__(256)
void maxpool_p1(const bf16_t* __restrict__ lo, float* __restrict__ part)
{
    int sc = blockIdx.x, b = blockIdx.y;       // 32 chunks x 8 batches
    int tid = threadIdx.x;
    const bf16_t* p = lo + ((long long)b * SS + sc * 32) * HH;
    float m[6];
    #pragma unroll
    for (int k = 0; k < 6; k++) m[k] = -1e30f;
    for (int r = 0; r < 32; r++)
        #pragma unroll
        for (int k = 0; k < 6; k++)
            m[k] = fmaxf(m[k], (float)p[(long long)r * HH + k * 256 + tid]);
    #pragma unroll
    for (int k = 0; k < 6; k++)
        part[((long long)b * 32 + sc) * HH + k * 256 + tid] = m[k];
}

__global__ __launch_bounds__(256)
void maxpool_p2(const float* __restrict__ part, float* __restrict__ pooled)
{
    int i = blockIdx.x * 256 + threadIdx.x;    // < B*H
    if (i >= BB * HH) return;
    int b = i / HH, c = i % HH;
    float m = -1e30f;
    for (int ch = 0; ch < 32; ch++) m = fmaxf(m, part[((long long)b * 32 + ch) * HH + c]);
    pooled[i] = m;
}

// logits[b] = pooled[b,:] . wd + bd
__global__ __launch_bounds__(256)
void decoder_kernel(const float* __restrict__ pooled, const void* __restrict__ wd,
                    const void* __restrict__ bd, void* __restrict__ out,
                    const int* __restrict__ flagp)
{
    int isbf = *flagp;
    int b = blockIdx.x;
    int tid = threadIdx.x;
    float s = 0.0f;
    #pragma unroll
    for (int i = 0; i < 6; i++) {
        int c = tid + i * 256;
        s += pooled[b * HH + c] * rd_adapt(wd, c, isbf);
    }
    __shared__ float sa[256];
    sa[tid] = s; __syncthreads();
    for (int o = 128; o > 0; o >>= 1) { if (tid < o) sa[tid] += sa[tid + o]; __syncthreads(); }
    if (tid == 0) {
        float r = sa[0] + rd_adapt(bd, 0, isbf);
        if (isbf) ((bf16_t*)out)[b] = (bf16_t)r;
        else      ((float*)out)[b]  = r;
    }
}

// ---------------------------------------------------------------------------
extern "C" void kernel_launch(void* const* d_in, const int* in_sizes, int n_in,
                              void* d_out, int out_size, void* d_ws, size_t ws_size,
                              hipStream_t stream)
{
    const void* embed = d_in[0];
    const void* wq  = d_in[1];  const void* bq  = d_in[2];
    const void* wk  = d_in[3];  const void* bk  = d_in[4];
    const void* wv  = d_in[5];  const void* bv  = d_in[6];
    const void* dw  = d_in[7];  const void* pw  = d_in[8];  const void* sep_b = d_in[9];
    const void* wck = d_in[10]; const void* bck = d_in[11];
    const void* wco = d_in[12]; const void* bco = d_in[13];
    const void* wso = d_in[14]; const void* bso = d_in[15];
    const void* ln1g = d_in[16]; const void* ln1b = d_in[17];
    const void* wi  = d_in[18]; const void* bi  = d_in[19];
    const void* wo  = d_in[20]; const void* bo  = d_in[21];
    const void* ln2g = d_in[22]; const void* ln2b = d_in[23];
    const void* wd  = d_in[24]; const void* bd  = d_in[25];
    (void)ws_size; (void)in_sizes; (void)n_in; (void)out_size;

    // ---- arena (143.2 MB), lifetime-aliased (identical to round 6) ----
    char* ws = (char*)d_ws;
    char* A  = ws;                          // 50.33 MB: qkvco -> ybuf/interb/lout
    char* B  = ws + 50331648;               // 25.17 MB: wT_all -> dconvb -> ckb/ckp -> vT -> wiT/woT
    char* C_ = ws + 75497472;               // 12.58 MB: sepb -> mpart
    char* D  = ws + 88080384;               // 25.17 MB: ctxcat -> attn
    char* E  = ws + 113246208;              // 25.17 MB: ebuf -> y2
    char* F  = ws + 138412032;              //  4.72 MB: wT (pw / wck / wso)
    char* XP = ws + 143130624;              //  flag + pooled + cbias

    bf16_t* qkvco  = (bf16_t*)A;                    // [8192,3072]
    bf16_t* ybuf   = (bf16_t*)A;                    // [8192,1536] (after flash)
    bf16_t* interb = (bf16_t*)A;                    // [8192,3072] (after ln1)
    bf16_t* lout   = (bf16_t*)A;                    // [8192,1536] (after wo)
    bf16_t* wT_all = (bf16_t*)B;                    // [3072,1536] (merged gemm)
    bf16_t* dconvb = (bf16_t*)B;                    // [8192,1536] (after merged)
    bf16_t* ckb    = (bf16_t*)B;                    // [8192,64]   (after sep)
    float*  ckp    = (float*)(B + 1310720);         // [8192,56] f32
    bf16_t* vT     = (bf16_t*)B;                    // [8,768,1024] (after conv_out)
    bf16_t* wfT    = (bf16_t*)B;                    // wiT [3072,1536] / woT [1536,3072]
    bf16_t* sepb   = (bf16_t*)C_;                   // [8192,768]
    float*  mpart  = (float*)C_;                    // [8,32,1536] f32
    bf16_t* ctxcat = (bf16_t*)D;                    // [8192,1536]
    bf16_t* attn   = (bf16_t*)D;                    // [8192,1536]
    bf16_t* ebuf   = (bf16_t*)E;                    // [8192,1536]
    bf16_t* y2     = (bf16_t*)E;                    // [8192,1536]
    bf16_t* wT     = (bf16_t*)F;
    int*    flag   = (int*)XP;
    float*  pooled = (float*)(XP + 256);            // [8,1536] f32
    bf16_t* cbias  = (bf16_t*)(XP + 256 + 49152);   // [3072]

    dim3 blk(256);

    // big GEMMs: 256x256 8-phase pipeline (M%256==0, N%256==0, Kd%64==0)
    auto gemm_big = [&](const bf16_t* Ai, const bf16_t* Bt, bf16_t* Ci, const void* bias,
                        const bf16_t* emul, int lde, const int* fl,
                        int M, int N, int Kd, int lda, int ldb, int ldc, int act) {
        int tn = N / 256;
        dim3 g((M / 256) * tn);
        gemm256<<<g, dim3(512), 0, stream>>>(Ai, Bt, Ci, bias, emul, lde, fl,
                                             M, N, Kd, lda, ldb, ldc, act, tn);
    };
    // legacy 128x128 path (ck GEMM only)
    auto gemm = [&](const bf16_t* Ai, const bf16_t* Bt, bf16_t* Ci, const void* bias,
                    long long biasOff, const bf16_t* emul, int lde, const int* fl,
                    int M, int N, int Kd, int lda, int ldb, int ldc,
                    float scale, int act, int beta, int nlim) {
        dim3 g(M / 128, (N + 127) / 128, 1);
        gemm_tile<<<g, blk, 0, stream>>>(Ai, Bt, Ci, bias, biasOff, emul, lde, fl,
                                         M, N, Kd, lda, ldb, ldc,
                                         scale, act, beta, nlim);
    };
    auto transpose = [&](const void* in, bf16_t* out, int R, int Cc, int Cpad, int ldin,
                         long long inOff, int batch, long long sInB, long long sOutB,
                         const int* fl) {
        dim3 g(Cpad / 32, R / 32, batch);
        transpose_pad<<<g, blk, 0, stream>>>(in, out, R, Cc, ldin, inOff, sInB, sOutB, fl);
    };

    // --- dtype probe + embed conversion ---
    detect_kernel<<<dim3(1), blk, 0, stream>>>(embed, flag);
    convert_embed<<<dim3(6144), blk, 0, stream>>>(embed, ebuf, flag);

    // --- merged Q|K|V|co projection: [8192,1536] x [3072,1536]^T -> [8192,3072] ---
    transpose(wq,  wT_all + 0ll * 768 * 1536, 1536, 768, 768, 768, 0, 1, 0, 0, flag);
    transpose(wk,  wT_all + 1ll * 768 * 1536, 1536, 768, 768, 768, 0, 1, 0, 0, flag);
    transpose(wv,  wT_all + 2ll * 768 * 1536, 1536, 768, 768, 768, 0, 1, 0, 0, flag);
    transpose(wco, wT_all + 3ll * 768 * 1536, 1536, 768, 768, 768, 0, 1, 0, 0, flag);
    concat_bias<<<dim3(12), blk, 0, stream>>>(bq, bk, bv, bco, cbias, flag);
    gemm_big(ebuf, wT_all, qkvco, cbias, nullptr, 0, nullptr,
             8192, 3072, 1536, HH, HH, 3072, 0);

    // --- separable conv: depthwise, then pointwise fused with *q ---
    dconv_kernel<<<dim3((BB * SS * HH) / 256), blk, 0, stream>>>(ebuf, dw, dconvb, flag);
    transpose(pw, wT, 1536, 768, 768, 768, 0, 1, 0, 0, flag);
    gemm_big(dconvb, wT, sepb, sep_b, qkvco, 3072, flag,
             8192, 768, 1536, HH, HH, AHH, 0);

    // --- span conv kernels (wckT padded to 128 rows) ---
    transpose(wck, wT, 768, 56, 128, 56, 0, 1, 0, 0, flag);
    gemm(sepb, wT, ckb, bck, 0, nullptr, 0, flag,
         8192, 56, 768, AHH, AHH, 64, 1.0f, 0, 0, 127);
    ck_softmax<<<dim3((BB * SS * NHH) / 256), blk, 0, stream>>>(ckb, ckp);
    conv_out_kernel<<<dim3((BB * SS * AHH) / 256), blk, 0, stream>>>(qkvco + 2304, 3072, ckp, ctxcat);

    // --- fused flash attention (XCD-local grid: bh fastest) ---
    transpose(qkvco, vT, 1024, 768, 768, 3072, 1536, 8, 1024ll * 3072, 768ll * 1024, nullptr);
    flash_attn<<<dim3(64, 8), blk, 0, stream>>>(qkvco, vT, ctxcat);

    // --- self output + LN1 ---
    transpose(wso, wT, 1536, 1536, 1536, 1536, 0, 1, 0, 0, flag);
    gemm_big(ctxcat, wT, ybuf, bso, nullptr, 0, flag,
             8192, 1536, 1536, HH, HH, HH, 0);
    ln_kernel<<<dim3(8192), blk, 0, stream>>>(ybuf, ebuf, ln1g, ln1b, attn, flag);

    // --- FFN full-width + LN2 ---
    transpose(wi, wfT, 1536, 3072, 3072, 3072, 0, 1, 0, 0, flag);      // wiT [3072,1536]
    gemm_big(attn, wfT, interb, bi, nullptr, 0, flag,
             8192, 3072, 1536, HH, HH, IMM, 1);
    transpose(wo, wfT, 3072, 1536, 1536, 1536, 0, 1, 0, 0, flag);      // woT [1536,3072]
    gemm_big(interb, wfT, y2, bo, nullptr, 0, flag,
             8192, 1536, 3072, IMM, IMM, HH, 0);
    ln_kernel<<<dim3(8192), blk, 0, stream>>>(y2, attn, ln2g, ln2b, lout, flag);

    // --- pool + decode (partials in dead sepb slot) ---
    maxpool_p1<<<dim3(32, 8), blk, 0, stream>>>(lout, mpart);
    maxpool_p2<<<dim3(48), blk, 0, stream>>>(mpart, pooled);
    decoder_kernel<<<dim3(BB), blk, 0, stream>>>(pooled, wd, bd, d_out, flag);
}

// Round 2
// 890.293 us; speedup vs baseline: 1.0607x; 1.0607x over previous
//
#include <hip/hip_runtime.h>

// ---------------------------------------------------------------------------
// ConvBERT layer forward, bf16 compute / fp32 accumulate.
// B=8 S=1024 H=1536 NH=8 HD=96 AH=768 K=7 IM=3072
// Round 9: gemm256 v2 — software-pipelined frag reads (phase p issues phase
//          p+1's ds_reads, counted lgkmcnt keeps them in flight under the
//          MFMA cluster = the "derived waits" the m201 template relies on),
//          5 barriers/K-tile, vmcnt(4) once per tile. sep GEMM routed back
//          to the 128x128 kernel (N=768 -> only 96 WGs at 256 tile).
// ---------------------------------------------------------------------------

typedef __bf16 bf16_t;
typedef short s16x8 __attribute__((ext_vector_type(8)));   // 8 bf16 in 4 VGPRs
typedef float f32x4 __attribute__((ext_vector_type(4)));

#define BB  8
#define SS  1024
#define HH  1536
#define NHH 8
#define HDD 96
#define AHH 768
#define IMM 3072

__device__ __forceinline__ float rd_adapt(const void* p, long long i, int isbf) {
    return isbf ? (float)((const bf16_t*)p)[i] : ((const float*)p)[i];
}

// tanh-form GELU: max |diff| vs exact erf-GELU ~3e-3, far under bf16 budget
__device__ __forceinline__ float gelu_f(float v) {
    float u = v * (0.7978845608f + 0.0356774081f * v * v);
    float e = __expf(2.0f * u);
    float t = 1.0f - 2.0f / (e + 1.0f);
    return 0.5f * v * (1.0f + t);
}

// async global->LDS, 16B per lane; lds base must be wave-uniform
__device__ __forceinline__ void gl2lds16(const bf16_t* g, bf16_t* l) {
    __builtin_amdgcn_global_load_lds(
        (__attribute__((address_space(1))) const void*)g,
        (__attribute__((address_space(3))) void*)l, 16, 0, 0);
}

#define FENCE() asm volatile("" ::: "memory")
#define BARRIER() do { FENCE(); __builtin_amdgcn_s_barrier(); FENCE(); } while (0)

// ---------------------------------------------------------------------------
// dtype probe: bf16 vs fp32 inputs. flag=1 -> bf16.
// ---------------------------------------------------------------------------
__global__ __launch_bounds__(256)
void detect_kernel(const void* __restrict__ embed, int* __restrict__ flag)
{
    __shared__ int cnt[256];
    int t = threadIdx.x;
    float x = (float)((const bf16_t*)embed)[t];
    float a = fabsf(x);
    cnt[t] = (a > 1e-3f && a < 50.0f) ? 1 : 0;
    __syncthreads();
    for (int o = 128; o > 0; o >>= 1) { if (t < o) cnt[t] += cnt[t + o]; __syncthreads(); }
    if (t == 0) *flag = (cnt[0] >= 205) ? 1 : 0;
}

__global__ __launch_bounds__(256)
void convert_embed(const void* __restrict__ in, bf16_t* __restrict__ out,
                   const int* __restrict__ flagp)
{
    int isbf = *flagp;
    long long i0 = ((long long)blockIdx.x * 256 + threadIdx.x) * 8;
    if (isbf) {
        *(s16x8*)(out + i0) = *(const s16x8*)((const bf16_t*)in + i0);
    } else {
        const float* f = (const float*)in;
        #pragma unroll
        for (int j = 0; j < 8; j++) out[i0 + j] = (bf16_t)f[i0 + j];
    }
}

// concat bq|bk|bv|bco -> cbias[3072] bf16
__global__ __launch_bounds__(256)
void concat_bias(const void* __restrict__ b0, const void* __restrict__ b1,
                 const void* __restrict__ b2, const void* __restrict__ b3,
                 bf16_t* __restrict__ out, const int* __restrict__ flagp)
{
    int isbf = *flagp;
    int t = blockIdx.x * 256 + threadIdx.x;   // < 3072
    int sel = t / 768, off = t - sel * 768;
    const void* src = (sel == 0) ? b0 : (sel == 1) ? b1 : (sel == 2) ? b2 : b3;
    out[t] = (bf16_t)rd_adapt(src, off, isbf);
}

// ---------------------------------------------------------------------------
// gemm256 v2: 256x256 tile, BK=64, 512 threads = 8 waves (2M x 4N).
// Read batches per tile t (all from current buffer):
//   R1 = af0 (A rows wm*128+0..63, 8 rd) + bf0 (B rows wn*64+0..31, 4 rd)
//   R2 = bf1 (B rows wn*64+32..63, 4 rd)
//   R3 = af1 (A rows wm*128+64..127, 8 rd)
// Pipeline: R_{p+1} issued in phase p, waited with counted lgkmcnt before
// phase p+1's MFMA -> reads complete UNDER the MFMA cluster.
//   ph1: issue R2, stage A-h1(t+1)->ob, lgkm(4),  MFMA af0 x bf0 -> acc[0..3][0..1]
//   ph2: issue R3, stage B-h1(t+1)->ob, lgkm(8),  MFMA af0 x bf1 -> acc[0..3][2..3]
//   ph3:           stage B-h0(t+2)->cur, lgkm(0), MFMA af1 x bf1 -> acc[4..7][2..3]
//   ph4: stage A-h0(t+2)->cur; vmcnt(4); barrier (t+1 landed for ALL waves);
//        issue af0'(t+1); MFMA af1 x bf0 -> acc[4..7][0..1]; issue bf0'(t+1)
// vmcnt(4) leaves exactly ph3(t)+ph4(t) stages outstanding = drains all four
// t+1 half-tiles (staged ph3(t-1), ph4(t-1), ph1(t), ph2(t)).
// Requires M%256==0, N%256==0, Kd%64==0.
// ---------------------------------------------------------------------------
__global__ __launch_bounds__(512, 2)
void gemm256(const bf16_t* __restrict__ A, const bf16_t* __restrict__ Bt,
             bf16_t* __restrict__ C, const void* __restrict__ bias,
             const bf16_t* __restrict__ emul, int lde, const int* __restrict__ flagp,
             int M, int N, int Kd, int lda, int ldb, int ldc, int act, int tilesN)
{
    __shared__ bf16_t Sm[65536];   // 128 KiB
    char* smb = (char*)Sm;
    int isbf = flagp ? *flagp : 1;

    // bijective XCD remap (m204) of the linear tile id; n fastest inside
    int nwg = gridDim.x;
    int orig = blockIdx.x;
    int q = nwg >> 3, r = nwg & 7;
    int xcd = orig & 7, lid = orig >> 3;
    int wg = (xcd < r ? xcd * (q + 1) : r * (q + 1) + (xcd - r) * q) + lid;
    int row0 = (wg / tilesN) * 256;
    int col0 = (wg % tilesN) * 256;

    int tid = threadIdx.x;
    int wave = tid >> 6, lane = tid & 63;
    int wm = wave >> 2, wn = wave & 3;
    int lm = lane & 15, kq = lane >> 4;

    // ---- staging geometry: wave w loads chunks {2w,2w+1} of each 16KB half
    int srow = lane >> 3;                       // 0..7 row within 1KB chunk
    int scol = 8 * ((lane & 7) ^ srow);         // pre-swizzled source col (bf16)

    auto stageA2 = [&](int kt, int h, int bufo) {
        #pragma unroll
        for (int l = 0; l < 2; l++) {
            int rloc = h * 128 + (2 * wave + l) * 8 + srow;
            gl2lds16(A + (long long)(row0 + rloc) * lda + kt * 64 + scol,
                     (bf16_t*)(smb + bufo * 32768 + h * 16384 + (2 * wave + l) * 1024));
        }
    };
    auto stageB2 = [&](int kt, int h, int bufo) {
        #pragma unroll
        for (int l = 0; l < 2; l++) {
            int rloc = h * 128 + (2 * wave + l) * 8 + srow;
            gl2lds16(Bt + (long long)(col0 + rloc) * ldb + kt * 64 + scol,
                     (bf16_t*)(smb + 65536 + bufo * 32768 + h * 16384 + (2 * wave + l) * 1024));
        }
    };

    // ---- fragment-read address constants (swizzled) ----
    int xo = (lm & 7) << 4;
    int cofs[2];                                // byte col offset for ksub 0/1
    cofs[0] = (kq * 16) ^ xo;
    cofs[1] = (64 + kq * 16) ^ xo;
    int aoffs[8];
    #pragma unroll
    for (int ip = 0; ip < 8; ip++) aoffs[ip] = (wm * 128 + ip * 16 + lm) * 128;
    int boffs[4];
    #pragma unroll
    for (int j = 0; j < 4; j++) boffs[j] = 65536 + (wn * 64 + j * 16 + lm) * 128;

    f32x4 acc[8][4] = {};
    s16x8 af0[4][2], af1[4][2], bf0[2][2], bf1[2][2];

    int KT = Kd >> 6;

    // ---- prologue: tile0 (4 halves, 8 loads) + t=1's B-h0/A-h0 (4 loads) ----
    stageA2(0, 0, 0);
    stageA2(0, 1, 0);
    stageB2(0, 0, 0);
    stageB2(0, 1, 0);
    int k1 = min(1, KT - 1);
    stageB2(k1, 0, 1);
    stageA2(k1, 0, 1);
    asm volatile("s_waitcnt vmcnt(4)" ::: "memory");   // tile0 landed; t=1 halves remain
    BARRIER();
    // R1(0): af0 + bf0 from buf0
    #pragma unroll
    for (int i = 0; i < 4; i++)
        #pragma unroll
        for (int s = 0; s < 2; s++)
            af0[i][s] = *(const s16x8*)(smb + aoffs[i] + cofs[s]);
    #pragma unroll
    for (int j = 0; j < 2; j++)
        #pragma unroll
        for (int s = 0; s < 2; s++)
            bf0[j][s] = *(const s16x8*)(smb + boffs[j] + cofs[s]);

    for (int t = 0; t < KT; t++) {
        int buf = t & 1;
        int bA = buf * 32768;
        int ob = buf ^ 1;
        int bN = ob * 32768;
        int tn1 = min(t + 1, KT - 1), tn2 = min(t + 2, KT - 1);

        // ---------------- phase 1 ----------------
        BARRIER();
        #pragma unroll
        for (int j = 0; j < 2; j++)
            #pragma unroll
            for (int s = 0; s < 2; s++)
                bf1[j][s] = *(const s16x8*)(smb + bA + boffs[2 + j] + cofs[s]);   // R2
        stageA2(tn1, 1, ob);
        asm volatile("s_waitcnt lgkmcnt(4)" ::: "memory");   // R1 done, R2 in flight
        __builtin_amdgcn_sched_barrier(0);
        __builtin_amdgcn_s_setprio(1);
        #pragma unroll
        for (int i = 0; i < 4; i++)
            #pragma unroll
            for (int j = 0; j < 2; j++) {
                acc[i][j] = __builtin_amdgcn_mfma_f32_16x16x32_bf16(af0[i][0], bf0[j][0], acc[i][j], 0, 0, 0);
                acc[i][j] = __builtin_amdgcn_mfma_f32_16x16x32_bf16(af0[i][1], bf0[j][1], acc[i][j], 0, 0, 0);
            }
        __builtin_amdgcn_s_setprio(0);

        // ---------------- phase 2 ----------------
        BARRIER();
        #pragma unroll
        for (int i = 0; i < 4; i++)
            #pragma unroll
            for (int s = 0; s < 2; s++)
                af1[i][s] = *(const s16x8*)(smb + bA + aoffs[4 + i] + cofs[s]);   // R3
        stageB2(tn1, 1, ob);
        asm volatile("s_waitcnt lgkmcnt(8)" ::: "memory");   // R2 done, R3 in flight
        __builtin_amdgcn_sched_barrier(0);
        __builtin_amdgcn_s_setprio(1);
        #pragma unroll
        for (int i = 0; i < 4; i++)
            #pragma unroll
            for (int j = 0; j < 2; j++) {
                acc[i][2 + j] = __builtin_amdgcn_mfma_f32_16x16x32_bf16(af0[i][0], bf1[j][0], acc[i][2 + j], 0, 0, 0);
                acc[i][2 + j] = __builtin_amdgcn_mfma_f32_16x16x32_bf16(af0[i][1], bf1[j][1], acc[i][2 + j], 0, 0, 0);
            }
        __builtin_amdgcn_s_setprio(0);

        // ---------------- phase 3 ----------------
        BARRIER();
        stageB2(tn2, 0, buf);
        asm volatile("s_waitcnt lgkmcnt(0)" ::: "memory");   // R3 done
        __builtin_amdgcn_sched_barrier(0);
        __builtin_amdgcn_s_setprio(1);
        #pragma unroll
        for (int i = 0; i < 4; i++)
            #pragma unroll
            for (int j = 0; j < 2; j++) {
                acc[4 + i][2 + j] = __builtin_amdgcn_mfma_f32_16x16x32_bf16(af1[i][0], bf1[j][0], acc[4 + i][2 + j], 0, 0, 0);
                acc[4 + i][2 + j] = __builtin_amdgcn_mfma_f32_16x16x32_bf16(af1[i][1], bf1[j][1], acc[4 + i][2 + j], 0, 0, 0);
            }
        __builtin_amdgcn_s_setprio(0);

        // ---------------- phase 4 ----------------
        BARRIER();
        stageA2(tn2, 0, buf);
        asm volatile("s_waitcnt vmcnt(4)" ::: "memory");   // t+1 fully landed (this wave)
        BARRIER();                                          // ...and for all waves
        // issue af0'(t+1) from other buffer (af0 dead after ph2) -> overlaps MFMA4
        #pragma unroll
        for (int i = 0; i < 4; i++)
            #pragma unroll
            for (int s = 0; s < 2; s++)
                af0[i][s] = *(const s16x8*)(smb + bN + aoffs[i] + cofs[s]);
        __builtin_amdgcn_s_setprio(1);
        #pragma unroll
        for (int i = 0; i < 4; i++)
            #pragma unroll
            for (int j = 0; j < 2; j++) {
                acc[4 + i][j] = __builtin_amdgcn_mfma_f32_16x16x32_bf16(af1[i][0], bf0[j][0], acc[4 + i][j], 0, 0, 0);
                acc[4 + i][j] = __builtin_amdgcn_mfma_f32_16x16x32_bf16(af1[i][1], bf0[j][1], acc[4 + i][j], 0, 0, 0);
            }
        __builtin_amdgcn_s_setprio(0);
        // issue bf0'(t+1) after bf0's last use -> completes under next barrier
        #pragma unroll
        for (int j = 0; j < 2; j++)
            #pragma unroll
            for (int s = 0; s < 2; s++)
                bf0[j][s] = *(const s16x8*)(smb + bN + boffs[j] + cofs[s]);
    }

    // ---- epilogue: D row = kq*4 + r, col = lm (m89/m91-verified) ----
    #pragma unroll
    for (int j = 0; j < 4; j++) {
        int gcol = col0 + wn * 64 + j * 16 + lm;
        float bv = bias ? rd_adapt(bias, gcol, isbf) : 0.0f;
        #pragma unroll
        for (int ip = 0; ip < 8; ip++) {
            int grow0 = row0 + wm * 128 + ip * 16 + kq * 4;
            #pragma unroll
            for (int r = 0; r < 4; r++) {
                float v = acc[ip][j][r] + bv;
                if (emul) v *= (float)emul[(long long)(grow0 + r) * lde + gcol];
                if (act) v = gelu_f(v);
                C[(long long)(grow0 + r) * ldc + gcol] = (bf16_t)v;
            }
        }
    }
}

// ---------------------------------------------------------------------------
// Legacy 128x128 GEMM (sep + tiny ck GEMM).
// ---------------------------------------------------------------------------
__global__ __launch_bounds__(256)
void gemm_tile(const bf16_t* __restrict__ A, const bf16_t* __restrict__ Bt,
               bf16_t* __restrict__ C, const void* __restrict__ bias, long long biasOff,
               const bf16_t* __restrict__ emul, int lde, const int* __restrict__ flagp,
               int M, int N, int Kd, int lda, int ldb, int ldc,
               float scale, int act, int beta, int nlim)
{
    __shared__ bf16_t Sm[16384];   // As: [2][128][32] at 0; Bs: [2][128][32] at 8192

    int isbf = flagp ? *flagp : 1;
    int tid  = threadIdx.x;
    int wave = tid >> 6, lane = tid & 63;
    int wm = wave >> 1, wn = wave & 1;
    int row0 = blockIdx.x * 128;
    int col0 = blockIdx.y * 128;
    int lm = lane & 15;
    int kq = lane >> 4;

    int sr = tid >> 2;            // 0..63
    int sc = (tid & 3) * 8;       // 0,8,16,24
    const bf16_t* ga0 = A + (long long)(row0 + sr) * lda + sc;
    const bf16_t* ga1 = A + (long long)(row0 + 64 + sr) * lda + sc;
    int br0 = min(col0 + sr, nlim);
    int br1 = min(col0 + 64 + sr, nlim);
    const bf16_t* gb0 = Bt + (long long)br0 * ldb + sc;
    const bf16_t* gb1 = Bt + (long long)br1 * ldb + sc;
    bf16_t* lw = Sm + wave * 512;   // wave-uniform staging base

    f32x4 acc[4][4] = {};

    for (int k0 = 0; k0 < Kd; k0 += 64) {
        #pragma unroll
        for (int h = 0; h < 2; h++) {
            int kh = k0 + h * 32;
            gl2lds16(ga0 + kh, lw + h * 4096);
            gl2lds16(ga1 + kh, lw + h * 4096 + 2048);
            gl2lds16(gb0 + kh, lw + 8192 + h * 4096);
            gl2lds16(gb1 + kh, lw + 8192 + h * 4096 + 2048);
        }
        __syncthreads();

        s16x8 af[2][4], bfr[2][4];
        #pragma unroll
        for (int h = 0; h < 2; h++) {
            #pragma unroll
            for (int i = 0; i < 4; i++)
                af[h][i] = *(const s16x8*)(Sm + h * 4096 + (wm * 64 + i * 16 + lm) * 32 + kq * 8);
            #pragma unroll
            for (int j = 0; j < 4; j++)
                bfr[h][j] = *(const s16x8*)(Sm + 8192 + h * 4096 + (wn * 64 + j * 16 + lm) * 32 + kq * 8);
        }
        #pragma unroll
        for (int i = 0; i < 4; i++)
            #pragma unroll
            for (int j = 0; j < 4; j++) {
                acc[i][j] = __builtin_amdgcn_mfma_f32_16x16x32_bf16(af[0][i], bfr[0][j], acc[i][j], 0, 0, 0);
                acc[i][j] = __builtin_amdgcn_mfma_f32_16x16x32_bf16(af[1][i], bfr[1][j], acc[i][j], 0, 0, 0);
            }
        __syncthreads();
    }

    // epilogue: D row = kq*4 + r, col = lm (m89/m91-verified)
    #pragma unroll
    for (int j = 0; j < 4; j++) {
        int gcol = col0 + wn * 64 + j * 16 + lm;
        if (gcol >= N) continue;
        float bv = bias ? rd_adapt(bias, biasOff + gcol, isbf) : 0.0f;
        #pragma unroll
        for (int i = 0; i < 4; i++) {
            int grow0 = row0 + wm * 64 + i * 16 + kq * 4;
            #pragma unroll
            for (int r = 0; r < 4; r++) {
                float v = acc[i][j][r] * scale + bv;
                long long ci = (long long)(grow0 + r) * ldc + gcol;
                if (beta) v += (float)C[ci];
                if (emul) v *= (float)emul[(long long)(grow0 + r) * lde + gcol];
                if (act) v = gelu_f(v);
                C[ci] = (bf16_t)v;
            }
        }
    }
}

// ---------------------------------------------------------------------------
// Fused flash attention. grid = (64 bh, 8 q-tiles), block = 256.
// bh fastest -> XCD = bh%8 -> all q-tiles of one (b,h) share an XCD's L2.
// ---------------------------------------------------------------------------
__global__ __launch_bounds__(256, 2)
void flash_attn(const bf16_t* __restrict__ qkv, const bf16_t* __restrict__ vT,
                bf16_t* __restrict__ ctxcat)
{
    const float ascale = 0.1020620726159658f;   // 1/sqrt(96)
    __shared__ bf16_t Pl[4 * 32 * 136];         // per-wave P[32][136] (pad 8)

    int bh = blockIdx.x;
    int b = bh >> 3, h = bh & 7;
    const bf16_t* Qp = qkv  + (long long)b * SS * 3072 + h * HDD;
    const bf16_t* Kp = qkv  + (long long)b * SS * 3072 + 768 + h * HDD;
    const bf16_t* Vt = vT   + (long long)b * AHH * SS + (long long)h * HDD * SS;
    bf16_t*       Op = ctxcat + (long long)b * SS * HH + h * HDD;

    int tid = threadIdx.x, wave = tid >> 6, lane = tid & 63;
    int lm = lane & 15, kq = lane >> 4;
    int q0 = blockIdx.y * 128 + wave * 32;
    bf16_t* Pw = Pl + wave * 32 * 136;

    s16x8 aq[2][3];
    #pragma unroll
    for (int i = 0; i < 2; i++)
        #pragma unroll
        for (int kf = 0; kf < 3; kf++)
            aq[i][kf] = *(const s16x8*)(Qp + (long long)(q0 + i * 16 + lm) * 3072 + kf * 32 + kq * 8);

    f32x4 Oacc[2][6] = {};
    float mrow[2][4], lrow[2][4];
    #pragma unroll
    for (int i = 0; i < 2; i++)
        #pragma unroll
        for (int r = 0; r < 4; r++) { mrow[i][r] = -1e30f; lrow[i][r] = 0.0f; }

    for (int kt = 0; kt < 8; kt++) {
        f32x4 S[2][8] = {};
        #pragma unroll
        for (int j = 0; j < 8; j++) {
            s16x8 bk[3];
            #pragma unroll
            for (int kf = 0; kf < 3; kf++)
                bk[kf] = *(const s16x8*)(Kp + (long long)(kt * 128 + j * 16 + lm) * 3072 + kf * 32 + kq * 8);
            #pragma unroll
            for (int i = 0; i < 2; i++)
                #pragma unroll
                for (int kf = 0; kf < 3; kf++)
                    S[i][j] = __builtin_amdgcn_mfma_f32_16x16x32_bf16(aq[i][kf], bk[kf], S[i][j], 0, 0, 0);
        }

        float mnew[2][4];
        #pragma unroll
        for (int i = 0; i < 2; i++) {
            #pragma unroll
            for (int r = 0; r < 4; r++) {
                float mx = -1e30f;
                #pragma unroll
                for (int j = 0; j < 8; j++) mx = fmaxf(mx, S[i][j][r]);
                #pragma unroll
                for (int msk = 1; msk <= 8; msk <<= 1) mx = fmaxf(mx, __shfl_xor(mx, msk));
                mnew[i][r] = fmaxf(mrow[i][r], mx * ascale);
            }
        }
        #pragma unroll
        for (int i = 0; i < 2; i++) {
            #pragma unroll
            for (int r = 0; r < 4; r++) {
                float al = __expf(mrow[i][r] - mnew[i][r]);
                lrow[i][r] *= al;
                #pragma unroll
                for (int n = 0; n < 6; n++) Oacc[i][n][r] *= al;
                mrow[i][r] = mnew[i][r];
            }
        }
        float psum[2][4] = {};
        __syncthreads();
        #pragma unroll
        for (int i = 0; i < 2; i++) {
            #pragma unroll
            for (int j = 0; j < 8; j++) {
                #pragma unroll
                for (int r = 0; r < 4; r++) {
                    float p = __expf(S[i][j][r] * ascale - mnew[i][r]);
                    psum[i][r] += p;
                    Pw[(i * 16 + kq * 4 + r) * 136 + j * 16 + lm] = (bf16_t)p;
                }
            }
        }
        #pragma unroll
        for (int i = 0; i < 2; i++) {
            #pragma unroll
            for (int r = 0; r < 4; r++) {
                float t = psum[i][r];
                #pragma unroll
                for (int msk = 1; msk <= 8; msk <<= 1) t += __shfl_xor(t, msk);
                lrow[i][r] += t;
            }
        }
        __syncthreads();

        s16x8 ap[2][4];
        #pragma unroll
        for (int i = 0; i < 2; i++)
            #pragma unroll
            for (int kf = 0; kf < 4; kf++)
                ap[i][kf] = *(const s16x8*)(Pw + (i * 16 + lm) * 136 + kf * 32 + kq * 8);
        #pragma unroll
        for (int n = 0; n < 6; n++) {
            s16x8 bv[4];
            #pragma unroll
            for (int kf = 0; kf < 4; kf++)
                bv[kf] = *(const s16x8*)(Vt + (long long)(n * 16 + lm) * SS + kt * 128 + kf * 32 + kq * 8);
            #pragma unroll
            for (int i = 0; i < 2; i++)
                #pragma unroll
                for (int kf = 0; kf < 4; kf++)
                    Oacc[i][n] = __builtin_amdgcn_mfma_f32_16x16x32_bf16(ap[i][kf], bv[kf], Oacc[i][n], 0, 0, 0);
        }
    }

    #pragma unroll
    for (int i = 0; i < 2; i++) {
        #pragma unroll
        for (int n = 0; n < 6; n++) {
            #pragma unroll
            for (int r = 0; r < 4; r++) {
                int row = q0 + i * 16 + kq * 4 + r;
                int col = n * 16 + lm;
                Op[(long long)row * HH + col] = (bf16_t)(Oacc[i][n][r] / lrow[i][r]);
            }
        }
    }
}

// ---------------------------------------------------------------------------
// Adaptive tiled transpose with zero-padding beyond C columns.
// ---------------------------------------------------------------------------
__global__ __launch_bounds__(256)
void transpose_pad(const void* __restrict__ in, bf16_t* __restrict__ out,
                   int R, int C, int ldin, long long inOff,
                   long long sInB, long long sOutB, const int* __restrict__ flagp)
{
    __shared__ bf16_t t[32][33];
    int isbf = flagp ? *flagp : 1;
    int z = blockIdx.z;
    long long base = inOff + (long long)z * sInB;
    bf16_t* op = out + (long long)z * sOutB;
    int tx = threadIdx.x & 31, ty = threadIdx.x >> 5;
    int cb = blockIdx.x * 32, rb = blockIdx.y * 32;
    #pragma unroll
    for (int rr = ty; rr < 32; rr += 8) {
        int r = rb + rr, c = cb + tx;
        t[rr][tx] = (c < C) ? (bf16_t)rd_adapt(in, base + (long long)r * ldin + c, isbf)
                            : (bf16_t)0.0f;
    }
    __syncthreads();
    #pragma unroll
    for (int rr = ty; rr < 32; rr += 8) {
        int c = cb + rr;
        op[(long long)c * R + rb + tx] = t[tx][rr];
    }
}

// depthwise conv k=7, 'same' padding along S
__global__ __launch_bounds__(256)
void dconv_kernel(const bf16_t* __restrict__ ebuf, const void* __restrict__ dw,
                  bf16_t* __restrict__ out, const int* __restrict__ flagp)
{
    int isbf = *flagp;
    long long i = (long long)blockIdx.x * 256 + threadIdx.x;   // < B*S*H
    int c = (int)(i % HH);
    long long bs = i / HH;
    int s = (int)(bs % SS);
    float acc = 0.0f;
    #pragma unroll
    for (int k = 0; k < 7; k++) {
        int ss = s + k - 3;
        if (ss >= 0 && ss < SS)
            acc += (float)ebuf[(bs + (k - 3)) * HH + c] * rd_adapt(dw, c * 7 + k, isbf);
    }
    out[i] = (bf16_t)acc;
}

// ck softmax over k=7 per (b,s,h)
__global__ __launch_bounds__(256)
void ck_softmax(const bf16_t* __restrict__ ck, float* __restrict__ ckp)
{
    int i = blockIdx.x * 256 + threadIdx.x;   // < B*S*NH
    if (i >= BB * SS * NHH) return;
    int h = i % NHH;
    long long bs = i / NHH;
    const bf16_t* src = ck + bs * 64 + h * 7;
    float v[7], mx = -1e30f;
    #pragma unroll
    for (int k = 0; k < 7; k++) { v[k] = (float)src[k]; mx = fmaxf(mx, v[k]); }
    float sum = 0.0f;
    #pragma unroll
    for (int k = 0; k < 7; k++) { v[k] = expf(v[k] - mx); sum += v[k]; }
    float inv = 1.0f / sum;
    float* dst = ckp + bs * 56 + h * 7;
    #pragma unroll
    for (int k = 0; k < 7; k++) dst[k] = v[k] * inv;
}

// conv_out -> right half (cols 768..1535) of ctxcat; co has row stride ldco
__global__ __launch_bounds__(256)
void conv_out_kernel(const bf16_t* __restrict__ co, int ldco,
                     const float* __restrict__ ckp, bf16_t* __restrict__ ctxcat)
{
    long long i = (long long)blockIdx.x * 256 + threadIdx.x;   // < B*S*AH
    int hd = (int)(i % AHH);
    long long bs = i / AHH;
    int s = (int)(bs % SS);
    int h = hd / HDD;
    const float* w = ckp + bs * 56 + h * 7;
    float acc = 0.0f;
    #pragma unroll
    for (int k = 0; k < 7; k++) {
        int ss = s + k - 3;
        if (ss >= 0 && ss < SS)
            acc += (float)co[(bs + (k - 3)) * ldco + hd] * w[k];
    }
    ctxcat[bs * HH + AHH + hd] = (bf16_t)acc;
}

// LayerNorm over 1536 of (y + res)
__global__ __launch_bounds__(256)
void ln_kernel(const bf16_t* __restrict__ y, const bf16_t* __restrict__ res,
               const void* __restrict__ g, const void* __restrict__ bta,
               bf16_t* __restrict__ outb, const int* __restrict__ flagp)
{
    int isbf = *flagp;
    long long row = blockIdx.x;
    const bf16_t* yp = y + row * HH;
    const bf16_t* rp = res + row * HH;
    int tid = threadIdx.x;
    float x[6], s = 0.0f, s2 = 0.0f;
    #pragma unroll
    for (int i = 0; i < 6; i++) {
        int c = tid + i * 256;
        float v = (float)yp[c] + (float)rp[c];
        x[i] = v; s += v; s2 += v * v;
    }
    __shared__ float sa[256], sb[256];
    sa[tid] = s; sb[tid] = s2; __syncthreads();
    for (int o = 128; o > 0; o >>= 1) {
        if (tid < o) { sa[tid] += sa[tid + o]; sb[tid] += sb[tid + o]; }
        __syncthreads();
    }
    float mean = sa[0] * (1.0f / HH);
    float var  = sb[0] * (1.0f / HH) - mean * mean;
    float inv  = rsqrtf(var + 1e-12f);
    #pragma unroll
    for (int i = 0; i < 6; i++) {
        int c = tid + i * 256;
        float v = (x[i] - mean) * inv * rd_adapt(g, c, isbf) + rd_adapt(bta, c, isbf);
        outb[row * HH + c] = (bf16_t)v;
    }
}

// two-phase maxpool
__global__ __launch_bounds__(256)
void maxpool_p1(const bf16_t* __restrict__ lo, float* __restrict__ part)
{
    int sc = blockIdx.x, b = blockIdx.y;       // 32 chunks x 8 batches
    int tid = threadIdx.x;
    const bf16_t* p = lo + ((long long)b * SS + sc * 32) * HH;
    float m[6];
    #pragma unroll
    for (int k = 0; k < 6; k++) m[k] = -1e30f;
    for (int r = 0; r < 32; r++)
        #pragma unroll
        for (int k = 0; k < 6; k++)
            m[k] = fmaxf(m[k], (float)p[(long long)r * HH + k * 256 + tid]);
    #pragma unroll
    for (int k = 0; k < 6; k++)
        part[((long long)b * 32 + sc) * HH + k * 256 + tid] = m[k];
}

__global__ __launch_bounds__(256)
void maxpool_p2(const float* __restrict__ part, float* __restrict__ pooled)
{
    int i = blockIdx.x * 256 + threadIdx.x;    // < B*H
    if (i >= BB * HH) return;
    int b = i / HH, c = i % HH;
    float m = -1e30f;
    for (int ch = 0; ch < 32; ch++) m = fmaxf(m, part[((long long)b * 32 + ch) * HH + c]);
    pooled[i] = m;
}

// logits[b] = pooled[b,:] . wd + bd
__global__ __launch_bounds__(256)
void decoder_kernel(const float* __restrict__ pooled, const void* __restrict__ wd,
                    const void* __restrict__ bd, void* __restrict__ out,
                    const int* __restrict__ flagp)
{
    int isbf = *flagp;
    int b = blockIdx.x;
    int tid = threadIdx.x;
    float s = 0.0f;
    #pragma unroll
    for (int i = 0; i < 6; i++) {
        int c = tid + i * 256;
        s += pooled[b * HH + c] * rd_adapt(wd, c, isbf);
    }
    __shared__ float sa[256];
    sa[tid] = s; __syncthreads();
    for (int o = 128; o > 0; o >>= 1) { if (tid < o) sa[tid] += sa[tid + o]; __syncthreads(); }
    if (tid == 0) {
        float r = sa[0] + rd_adapt(bd, 0, isbf);
        if (isbf) ((bf16_t*)out)[b] = (bf16_t)r;
        else      ((float*)out)[b]  = r;
    }
}

// ---------------------------------------------------------------------------
extern "C" void kernel_launch(void* const* d_in, const int* in_sizes, int n_in,
                              void* d_out, int out_size, void* d_ws, size_t ws_size,
                              hipStream_t stream)
{
    const void* embed = d_in[0];
    const void* wq  = d_in[1];  const void* bq  = d_in[2];
    const void* wk  = d_in[3];  const void* bk  = d_in[4];
    const void* wv  = d_in[5];  const void* bv  = d_in[6];
    const void* dw  = d_in[7];  const void* pw  = d_in[8];  const void* sep_b = d_in[9];
    const void* wck = d_in[10]; const void* bck = d_in[11];
    const void* wco = d_in[12]; const void* bco = d_in[13];
    const void* wso = d_in[14]; const void* bso = d_in[15];
    const void* ln1g = d_in[16]; const void* ln1b = d_in[17];
    const void* wi  = d_in[18]; const void* bi  = d_in[19];
    const void* wo  = d_in[20]; const void* bo  = d_in[21];
    const void* ln2g = d_in[22]; const void* ln2b = d_in[23];
    const void* wd  = d_in[24]; const void* bd  = d_in[25];
    (void)ws_size; (void)in_sizes; (void)n_in; (void)out_size;

    // ---- arena (143.2 MB), lifetime-aliased (identical to round 6) ----
    char* ws = (char*)d_ws;
    char* A  = ws;                          // 50.33 MB: qkvco -> ybuf/interb/lout
    char* B  = ws + 50331648;               // 25.17 MB: wT_all -> dconvb -> ckb/ckp -> vT -> wiT/woT
    char* C_ = ws + 75497472;               // 12.58 MB: sepb -> mpart
    char* D  = ws + 88080384;               // 25.17 MB: ctxcat -> attn
    char* E  = ws + 113246208;              // 25.17 MB: ebuf -> y2
    char* F  = ws + 138412032;              //  4.72 MB: wT (pw / wck / wso)
    char* XP = ws + 143130624;              //  flag + pooled + cbias

    bf16_t* qkvco  = (bf16_t*)A;                    // [8192,3072]
    bf16_t* ybuf   = (bf16_t*)A;                    // [8192,1536] (after flash)
    bf16_t* interb = (bf16_t*)A;                    // [8192,3072] (after ln1)
    bf16_t* lout   = (bf16_t*)A;                    // [8192,1536] (after wo)
    bf16_t* wT_all = (bf16_t*)B;                    // [3072,1536] (merged gemm)
    bf16_t* dconvb = (bf16_t*)B;                    // [8192,1536] (after merged)
    bf16_t* ckb    = (bf16_t*)B;                    // [8192,64]   (after sep)
    float*  ckp    = (float*)(B + 1310720);         // [8192,56] f32
    bf16_t* vT     = (bf16_t*)B;                    // [8,768,1024] (after conv_out)
    bf16_t* wfT    = (bf16_t*)B;                    // wiT [3072,1536] / woT [1536,3072]
    bf16_t* sepb   = (bf16_t*)C_;                   // [8192,768]
    float*  mpart  = (float*)C_;                    // [8,32,1536] f32
    bf16_t* ctxcat = (bf16_t*)D;                    // [8192,1536]
    bf16_t* attn   = (bf16_t*)D;                    // [8192,1536]
    bf16_t* ebuf   = (bf16_t*)E;                    // [8192,1536]
    bf16_t* y2     = (bf16_t*)E;                    // [8192,1536]
    bf16_t* wT     = (bf16_t*)F;
    int*    flag   = (int*)XP;
    float*  pooled = (float*)(XP + 256);            // [8,1536] f32
    bf16_t* cbias  = (bf16_t*)(XP + 256 + 49152);   // [3072]

    dim3 blk(256);

    // big GEMMs: 256x256 pipelined 4-phase (M%256==0, N%256==0, Kd%64==0)
    auto gemm_big = [&](const bf16_t* Ai, const bf16_t* Bt, bf16_t* Ci, const void* bias,
                        const bf16_t* emul, int lde, const int* fl,
                        int M, int N, int Kd, int lda, int ldb, int ldc, int act) {
        int tn = N / 256;
        dim3 g((M / 256) * tn);
        gemm256<<<g, dim3(512), 0, stream>>>(Ai, Bt, Ci, bias, emul, lde, fl,
                                             M, N, Kd, lda, ldb, ldc, act, tn);
    };
    // legacy 128x128 path (sep + ck GEMM)
    auto gemm = [&](const bf16_t* Ai, const bf16_t* Bt, bf16_t* Ci, const void* bias,
                    long long biasOff, const bf16_t* emul, int lde, const int* fl,
                    int M, int N, int Kd, int lda, int ldb, int ldc,
                    float scale, int act, int beta, int nlim) {
        dim3 g(M / 128, (N + 127) / 128, 1);
        gemm_tile<<<g, blk, 0, stream>>>(Ai, Bt, Ci, bias, biasOff, emul, lde, fl,
                                         M, N, Kd, lda, ldb, ldc,
                                         scale, act, beta, nlim);
    };
    auto transpose = [&](const void* in, bf16_t* out, int R, int Cc, int Cpad, int ldin,
                         long long inOff, int batch, long long sInB, long long sOutB,
                         const int* fl) {
        dim3 g(Cpad / 32, R / 32, batch);
        transpose_pad<<<g, blk, 0, stream>>>(in, out, R, Cc, ldin, inOff, sInB, sOutB, fl);
    };

    // --- dtype probe + embed conversion ---
    detect_kernel<<<dim3(1), blk, 0, stream>>>(embed, flag);
    convert_embed<<<dim3(6144), blk, 0, stream>>>(embed, ebuf, flag);

    // --- merged Q|K|V|co projection: [8192,1536] x [3072,1536]^T -> [8192,3072] ---
    transpose(wq,  wT_all + 0ll * 768 * 1536, 1536, 768, 768, 768, 0, 1, 0, 0, flag);
    transpose(wk,  wT_all + 1ll * 768 * 1536, 1536, 768, 768, 768, 0, 1, 0, 0, flag);
    transpose(wv,  wT_all + 2ll * 768 * 1536, 1536, 768, 768, 768, 0, 1, 0, 0, flag);
    transpose(wco, wT_all + 3ll * 768 * 1536, 1536, 768, 768, 768, 0, 1, 0, 0, flag);
    concat_bias<<<dim3(12), blk, 0, stream>>>(bq, bk, bv, bco, cbias, flag);
    gemm_big(ebuf, wT_all, qkvco, cbias, nullptr, 0, nullptr,
             8192, 3072, 1536, HH, HH, 3072, 0);

    // --- separable conv: depthwise, then pointwise fused with *q (128^2 path) ---
    dconv_kernel<<<dim3((BB * SS * HH) / 256), blk, 0, stream>>>(ebuf, dw, dconvb, flag);
    transpose(pw, wT, 1536, 768, 768, 768, 0, 1, 0, 0, flag);
    gemm(dconvb, wT, sepb, sep_b, 0, qkvco, 3072, flag,
         8192, 768, 1536, HH, HH, AHH, 1.0f, 0, 0, 767);

    // --- span conv kernels (wckT padded to 128 rows) ---
    transpose(wck, wT, 768, 56, 128, 56, 0, 1, 0, 0, flag);
    gemm(sepb, wT, ckb, bck, 0, nullptr, 0, flag,
         8192, 56, 768, AHH, AHH, 64, 1.0f, 0, 0, 127);
    ck_softmax<<<dim3((BB * SS * NHH) / 256), blk, 0, stream>>>(ckb, ckp);
    conv_out_kernel<<<dim3((BB * SS * AHH) / 256), blk, 0, stream>>>(qkvco + 2304, 3072, ckp, ctxcat);

    // --- fused flash attention (XCD-local grid: bh fastest) ---
    transpose(qkvco, vT, 1024, 768, 768, 3072, 1536, 8, 1024ll * 3072, 768ll * 1024, nullptr);
    flash_attn<<<dim3(64, 8), blk, 0, stream>>>(qkvco, vT, ctxcat);

    // --- self output + LN1 ---
    transpose(wso, wT, 1536, 1536, 1536, 1536, 0, 1, 0, 0, flag);
    gemm_big(ctxcat, wT, ybuf, bso, nullptr, 0, flag,
             8192, 1536, 1536, HH, HH, HH, 0);
    ln_kernel<<<dim3(8192), blk, 0, stream>>>(ybuf, ebuf, ln1g, ln1b, attn, flag);

    // --- FFN full-width + LN2 ---
    transpose(wi, wfT, 1536, 3072, 3072, 3072, 0, 1, 0, 0, flag);      // wiT [3072,1536]
    gemm_big(attn, wfT, interb, bi, nullptr, 0, flag,
             8192, 3072, 1536, HH, HH, IMM, 1);
    transpose(wo, wfT, 3072, 1536, 1536, 1536, 0, 1, 0, 0, flag);      // woT [1536,3072]
    gemm_big(interb, wfT, y2, bo, nullptr, 0, flag,
             8192, 1536, 3072, IMM, IMM, HH, 0);
    ln_kernel<<<dim3(8192), blk, 0, stream>>>(y2, attn, ln2g, ln2b, lout, flag);

    // --- pool + decode (partials in dead sepb slot) ---
    maxpool_p1<<<dim3(32, 8), blk, 0, stream>>>(lout, mpart);
    maxpool_p2<<<dim3(48), blk, 0, stream>>>(mpart, pooled);
    decoder_kernel<<<dim3(BB), blk, 0, stream>>>(pooled, wd, bd, d_out, flag);
}